// Round 4
// baseline (237.272 us; speedup 1.0000x reference)
//
#include <hip/hip_runtime.h>
#include <hip/hip_bf16.h>

// MHA: B=2, S=2048, D=1024, H=16, hd=64, fp32 in/out.
// Round 11: attn K/V staging converted to T14 async-STAGE split (m214v27):
//           global->reg loads issued under previous tile's compute, ds_write
//           after raw s_barrier (+waitcnt/sched_barrier, rule #18). LDS and
//           occupancy unchanged (34.8KB, 4 blocks/CU). No setprio (round-9/10
//           A/B: -8us). XCD grouping kept (FETCH 69.7->12.3 MB verified).
//           GEMMs byte-identical to round 10.

constexpr int D_MODEL = 1024;
constexpr int S_LEN   = 2048;
constexpr int BATCH   = 2;
constexpr int NH      = 16;
constexpr int HD      = 64;
constexpr int ROWS    = BATCH * S_LEN;  // 4096

typedef __attribute__((ext_vector_type(8))) short short8;
typedef __attribute__((ext_vector_type(4))) float float4a;

static __device__ __forceinline__ unsigned short f2bf(float f) {
  union { float f; unsigned u; } v{f};
  unsigned r = v.u + 0x7FFFu + ((v.u >> 16) & 1u);  // RNE
  return (unsigned short)(r >> 16);
}

static __device__ __forceinline__ unsigned pack_bf16(float a, float b) {
#if __has_builtin(__builtin_amdgcn_cvt_pk_bf16_f32)
  typedef __attribute__((ext_vector_type(2))) __bf16 bf16x2;
  union { bf16x2 v; unsigned u; } c;
  c.v = __builtin_amdgcn_cvt_pk_bf16_f32(a, b);
  return c.u;
#else
  return (unsigned)f2bf(a) | ((unsigned)f2bf(b) << 16);
#endif
}

static __device__ __forceinline__ float bf2f(unsigned short u) {
  union { unsigned u; float f; } v;
  v.u = (unsigned)u << 16;
  return v.f;
}

// async 16B/lane global -> LDS
static __device__ __forceinline__ void async16(const void* g, void* l) {
  __builtin_amdgcn_global_load_lds(
      (const __attribute__((address_space(1))) unsigned int*)g,
      (__attribute__((address_space(3))) unsigned int*)l, 16, 0, 0);
}

// ---------------- fp32 -> bf16 convert ----------------
struct ConvArgs { const float* s[7]; unsigned short* d[7]; int n[7]; };

__global__ __launch_bounds__(256) void convert_bf16(ConvArgs a) {
  const int which = blockIdx.y;
  const int i = (blockIdx.x * 256 + threadIdx.x) * 8;
  if (i >= a.n[which]) return;
  const float4* s = (const float4*)(a.s[which] + i);
  float4 x = s[0], y = s[1];
  unsigned t[4] = {pack_bf16(x.x, x.y), pack_bf16(x.z, x.w),
                   pack_bf16(y.x, y.y), pack_bf16(y.z, y.w)};
  *(short8*)(a.d[which] + i) = *(short8*)t;
}

// ---------------- MFMA bf16 GEMM: Y = A @ W^T (+bias) ----------------
// 128x128 block tile, BK=32, single-buffer DMA staging (16 KB LDS).
// LDS slot swizzle: slot(r,c) = r*4 + ((c + (r>>1)) & 3)  (16B chunks).
// MODE 0: bf16 head-major [B,H,S,64], value = (acc + bias)*scale
// MODE 2: bf16 V^T [B,H,64,S] (two-pass per-wave LDS transpose, Tb aliased)
template <int MODE>
static __device__ __forceinline__ void gemm_body(
    const unsigned short* __restrict__ A, const unsigned short* __restrict__ W,
    const float* __restrict__ bias, void* __restrict__ Yv, float scale,
    unsigned short* As, unsigned short* Bs, unsigned short* Tb) {
  const int tid = threadIdx.x;
  const int w = tid >> 6, lane = tid & 63;
  const int l15 = lane & 15, quad = lane >> 4;
  const int row0 = blockIdx.x * 128, col0 = blockIdx.y * 128;
  const int wm = (w & 1) * 64, wn = (w >> 1) * 64;

  float4a acc[4][4];
#pragma unroll
  for (int i = 0; i < 4; i++)
#pragma unroll
    for (int j = 0; j < 4; j++) acc[i][j] = (float4a){0.f, 0.f, 0.f, 0.f};

  const int swA = (quad + (wm >> 1) + (l15 >> 1)) & 3;
  const int swB = (quad + (wn >> 1) + (l15 >> 1)) & 3;

  for (int kt = 0; kt < D_MODEL; kt += 32) {
    __syncthreads();  // prior ds_reads done before DMA overwrite
#pragma unroll
    for (int j = 0; j < 2; j++) {
      const int i = w * 2 + j;
      const int r = i * 16 + (lane >> 2);
      const int c = ((lane & 3) - (r >> 1)) & 3;
      async16(W + (size_t)(col0 + r) * D_MODEL + kt + c * 8, (char*)Bs + i * 1024);
      async16(A + (size_t)(row0 + r) * D_MODEL + kt + c * 8, (char*)As + i * 1024);
    }
    __syncthreads();  // drain vmcnt -> tiles resident

    short8 af[4], bf[4];
#pragma unroll
    for (int mt = 0; mt < 4; mt++) {
      const int r = wm + mt * 16 + l15;
      af[mt] = *(const short8*)&As[(r * 4 + swA) * 8];
    }
#pragma unroll
    for (int nt = 0; nt < 4; nt++) {
      const int r = wn + nt * 16 + l15;
      bf[nt] = *(const short8*)&Bs[(r * 4 + swB) * 8];
    }
#pragma unroll
    for (int mt = 0; mt < 4; mt++)
#pragma unroll
      for (int nt = 0; nt < 4; nt++)
        acc[mt][nt] = __builtin_amdgcn_mfma_f32_16x16x32_bf16(af[mt], bf[nt], acc[mt][nt], 0, 0, 0);
  }

  int cols[4];
  float bvs[4];
#pragma unroll
  for (int nt = 0; nt < 4; nt++) {
    cols[nt] = col0 + wn + nt * 16 + l15;
    bvs[nt]  = bias[cols[nt]] * ((MODE == 0) ? scale : 1.0f);
  }

  if constexpr (MODE == 0) {
    unsigned short* Y = (unsigned short*)Yv;
#pragma unroll
    for (int mt = 0; mt < 4; mt++)
#pragma unroll
      for (int r = 0; r < 4; r++) {
        const int m = row0 + wm + mt * 16 + quad * 4 + r;
        const int bb = m >> 11, s = m & 2047;
#pragma unroll
        for (int nt = 0; nt < 4; nt++) {
          const int h = cols[nt] >> 6, d = cols[nt] & 63;
          Y[(((size_t)(bb * NH + h)) * S_LEN + s) * HD + d] =
              f2bf(acc[mt][nt][r] * scale + bvs[nt]);
        }
      }
  } else {  // MODE 2: V^T, two-pass per-wave 64x32 transpose (Tb aliases staging)
    __syncthreads();  // all waves' K-loop LDS reads done before alias overwrite
    unsigned short* T = Tb + w * (64 * 32);  // 4 KB per wave
    unsigned short* Y = (unsigned short*)Yv;
#pragma unroll
    for (int p = 0; p < 2; p++) {
      if (p) { asm volatile("s_waitcnt lgkmcnt(0)" ::: "memory"); }  // pass-0 reads retired
#pragma unroll
      for (int mi = 0; mi < 2; mi++) {
        const int mt = 2 * p + mi;
#pragma unroll
        for (int r = 0; r < 4; r++) {
          const int sl = mi * 16 + quad * 4 + r;  // 0..31 within pass
          const int cch = sl >> 3;
#pragma unroll
          for (int nt = 0; nt < 4; nt++) {
            const int dl = nt * 16 + l15;
            const int slot = cch ^ (dl & 3);
            T[dl * 32 + slot * 8 + (sl & 7)] = f2bf(acc[mt][nt][r] + bvs[nt]);
          }
        }
      }
      asm volatile("s_waitcnt lgkmcnt(0)" ::: "memory");  // per-wave write->read
#pragma unroll
      for (int j = 0; j < 4; j++) {
        const int cid = j * 64 + lane;
        const int dl = cid >> 2;   // 0..63
        const int c  = cid & 3;    // s-chunk within pass
        const int slot = c ^ (dl & 3);
        short8 v = *(const short8*)&T[dl * 32 + slot * 8];
        const int col = col0 + wn + dl;
        const int h = col >> 6, d = col & 63;
        const int m = row0 + wm + p * 32 + c * 8;
        const int bb = m >> 11, s = m & 2047;
        *(short8*)&Y[(((size_t)(bb * NH + h)) * HD + d) * S_LEN + s] = v;
      }
    }
  }
}

__global__ __launch_bounds__(256) void gemm_qkv(
    const unsigned short* xq, const unsigned short* xk, const unsigned short* xv,
    const unsigned short* wq, const unsigned short* wk, const unsigned short* wv,
    const float* bq, const float* bk, const float* bv,
    unsigned short* Q, unsigned short* K, unsigned short* Vt) {
  __shared__ unsigned short smem[2 * 128 * 32];  // 16 KB: As + Bs; Tb aliases all
  unsigned short* As = smem;
  unsigned short* Bs = smem + 128 * 32;
  unsigned short* Tb = smem;
  const int z = blockIdx.z;
  // Q scale: 1/sqrt(64) * log2(e)  (softmax in exp2 domain)
  if (z == 0)      gemm_body<0>(xq, wq, bq, Q,  0.125f * 1.44269504f, As, Bs, Tb);
  else if (z == 1) gemm_body<0>(xk, wk, bk, K,  1.0f, As, Bs, Tb);
  else             gemm_body<2>(xv, wv, bv, Vt, 1.0f, As, Bs, Tb);
}

// ---------------- gemm_o with fused split-K merge ----------------
// out = ((O0+O1) * 1/(l0+l1)) @ Wo^T + bo.  64x128 tile, BK=32.
// A tile built in registers from bf16 partials (merge fused); W via DMA.
__global__ __launch_bounds__(256) void gemm_o(
    const unsigned short* __restrict__ Op, const float* __restrict__ Lp,
    const unsigned short* __restrict__ wo, const float* __restrict__ bo,
    float* __restrict__ out) {
  __shared__ unsigned short As[64 * 32];    // 4 KB
  __shared__ unsigned short Bs[128 * 32];   // 8 KB
  const int tid = threadIdx.x;
  const int w = tid >> 6, lane = tid & 63;
  const int l15 = lane & 15, quad = lane >> 4;
  const int row0 = blockIdx.x * 64, col0 = blockIdx.y * 128;
  const int wn = w * 32;

  // A-merge path: lane owns row ar, global k-chunk cg (8 bf16)
  const int ar = w * 16 + (lane >> 2);
  const int cg = lane & 3;
  const int asl = (cg + (ar >> 1)) & 3;  // LDS slot (same swizzle as DMA layout)
  const int grow = row0 + ar;
  const unsigned short* P0 = Op + (size_t)grow * D_MODEL + cg * 8;
  const unsigned short* P1 = P0 + (size_t)ROWS * D_MODEL;
  const float* L0 = Lp + (size_t)grow * NH;
  const float* L1 = L0 + (size_t)ROWS * NH;

  float4a acc[4][2];
#pragma unroll
  for (int i = 0; i < 4; i++)
#pragma unroll
    for (int j = 0; j < 2; j++) acc[i][j] = (float4a){0.f, 0.f, 0.f, 0.f};

  const int swA = (quad + (l15 >> 1)) & 3;
  const int swB = (quad + (wn >> 1) + (l15 >> 1)) & 3;

  for (int kt = 0; kt < D_MODEL; kt += 32) {
    const int h = kt >> 6;
    const float rinv = 1.0f / (L0[h] + L1[h]);
    short8 a = *(const short8*)(P0 + kt);
    short8 b = *(const short8*)(P1 + kt);
    unsigned t[4];
#pragma unroll
    for (int i = 0; i < 4; i++) {
      const float v0 = (bf2f((unsigned short)a[2 * i]) + bf2f((unsigned short)b[2 * i])) * rinv;
      const float v1 = (bf2f((unsigned short)a[2 * i + 1]) + bf2f((unsigned short)b[2 * i + 1])) * rinv;
      t[i] = pack_bf16(v0, v1);
    }
    __syncthreads();  // prior frag reads done before overwrite
    *(short8*)&As[(ar * 4 + asl) * 8] = *(short8*)t;
#pragma unroll
    for (int j = 0; j < 2; j++) {
      const int i = w * 2 + j;
      const int r = i * 16 + (lane >> 2);
      const int c = ((lane & 3) - (r >> 1)) & 3;
      async16(wo + (size_t)(col0 + r) * D_MODEL + kt + c * 8, (char*)Bs + i * 1024);
    }
    __syncthreads();  // drain vmcnt (DMA) + lgkm (ds_write)

    short8 af[4], bf[2];
#pragma unroll
    for (int mt = 0; mt < 4; mt++) {
      const int r = mt * 16 + l15;
      af[mt] = *(const short8*)&As[(r * 4 + swA) * 8];
    }
#pragma unroll
    for (int nt = 0; nt < 2; nt++) {
      const int r = wn + nt * 16 + l15;
      bf[nt] = *(const short8*)&Bs[(r * 4 + swB) * 8];
    }
#pragma unroll
    for (int mt = 0; mt < 4; mt++)
#pragma unroll
      for (int nt = 0; nt < 2; nt++)
        acc[mt][nt] = __builtin_amdgcn_mfma_f32_16x16x32_bf16(af[mt], bf[nt], acc[mt][nt], 0, 0, 0);
  }

#pragma unroll
  for (int nt = 0; nt < 2; nt++) {
    const int col = col0 + wn + nt * 16 + l15;
    const float bv = bo[col];
#pragma unroll
    for (int mt = 0; mt < 4; mt++)
#pragma unroll
      for (int r = 0; r < 4; r++) {
        const int m = row0 + mt * 16 + quad * 4 + r;
        out[(size_t)m * D_MODEL + col] = acc[mt][nt][r] + bv;
      }
  }
}

// ---------------- Flash attention, split-K x2, T14 async-STAGE ----------------
// Per KV-tile (KVBLK=64): next-tile K/V global->reg loads are issued under the
// CURRENT tile's compute; ds_write happens after B1 (all waves' reads done).
// Raw s_barrier + explicit waitcnt so barriers do NOT drain in-flight loads
// (unlike __syncthreads). LDS 34816 B -> 4 blocks/CU, same as round 10.
__global__ __launch_bounds__(256) void attn_kernel(
    const unsigned short* __restrict__ Qh, const unsigned short* __restrict__ Kh,
    const unsigned short* __restrict__ Vt, unsigned short* __restrict__ Op,
    float* __restrict__ Lp) {
  // grid = 1024 (1D). n&7 = XCD; 8 groups/XCD x 16 qb blocks = 128 blocks/XCD.
  const int n   = blockIdx.x;
  const int idx = n >> 3;
  const int qb  = idx & 15;
  const int g   = (n & 7) + 8 * (idx >> 4);  // 0..63
  const int h   = g & 15;
  const int z   = g >> 4;                    // 0..3
  const int bb  = z >> 1, sp = z & 1;

  const int tid = threadIdx.x;
  const int w = tid >> 6, lane = tid & 63;
  const int l15 = lane & 15, quad = lane >> 4;

  __shared__ unsigned short Ks[64 * 64];   // slot(r,c)=r*8+((c+r)&7), 16B chunks
  __shared__ unsigned short Vs[64 * 64];
  __shared__ unsigned short Ps[4][32][72];

  const size_t bh = (size_t)(bb * NH + h);
  const unsigned short* Qp = Qh + bh * S_LEN * HD;
  const unsigned short* Kp = Kh + bh * S_LEN * HD;
  const unsigned short* Vp = Vt + bh * (size_t)HD * S_LEN;

  // staging geometry (identical layout to the old DMA path):
  // chunk j in {0,1}: i = w*2+j, r = i*8 + (lane>>3), c = ((lane&7) - r) & 7
  // LDS dst = base + i*1024 + lane*16;  r1 = r0+8 -> same c.
  const int r0 = w * 16 + (lane >> 3);
  const int c0 = ((lane & 7) - r0) & 7;
  const unsigned short* Kg0 = Kp + (size_t)r0 * HD + c0 * 8;
  const unsigned short* Kg1 = Kg0 + 8 * HD;
  const unsigned short* Vg0 = Vp + (size_t)r0 * S_LEN + c0 * 8;
  const unsigned short* Vg1 = Vg0 + 8 * S_LEN;
  unsigned short* Kd0 = (unsigned short*)((char*)Ks + (w * 2) * 1024 + (size_t)lane * 16);
  unsigned short* Kd1 = (unsigned short*)((char*)Kd0 + 1024);
  unsigned short* Vd0 = (unsigned short*)((char*)Vs + (w * 2) * 1024 + (size_t)lane * 16);
  unsigned short* Vd1 = (unsigned short*)((char*)Vd0 + 1024);

  short8 qf[2][2];
#pragma unroll
  for (int qnt = 0; qnt < 2; qnt++)
#pragma unroll
    for (int c = 0; c < 2; c++)
      qf[qnt][c] = *(const short8*)(Qp + (size_t)(qb * 128 + w * 32 + qnt * 16 + l15) * HD +
                                    c * 32 + quad * 8);

  unsigned short ob[8] = {0x3F80, 0x3F80, 0x3F80, 0x3F80, 0x3F80, 0x3F80, 0x3F80, 0x3F80};
  const short8 ones = *(short8*)ob;

  float4a Oacc[2][4];
#pragma unroll
  for (int a = 0; a < 2; a++)
#pragma unroll
    for (int b = 0; b < 4; b++) Oacc[a][b] = (float4a){0.f, 0.f, 0.f, 0.f};
  float4a Lacc[2] = {(float4a){0.f, 0.f, 0.f, 0.f}, (float4a){0.f, 0.f, 0.f, 0.f}};

  const int sw0 = (quad + l15) & 7;
  const int sw1 = (quad + 4 + l15) & 7;

  const int kb0 = sp * 1024, kbend = kb0 + 1024;

  // prologue: stage tile 0 into regs
  short8 kr0 = *(const short8*)(Kg0 + (size_t)kb0 * HD);
  short8 kr1 = *(const short8*)(Kg1 + (size_t)kb0 * HD);
  short8 vr0 = *(const short8*)(Vg0 + kb0);
  short8 vr1 = *(const short8*)(Vg1 + kb0);

  for (int kb = kb0; kb < kbend; kb += 64) {
    // B1: all waves' LDS reads of the previous tile retired
    asm volatile("s_waitcnt lgkmcnt(0)" ::: "memory");
    __builtin_amdgcn_sched_barrier(0);
    __builtin_amdgcn_s_barrier();
    // staged data arrived (loads were issued one full compute phase ago)
    asm volatile("s_waitcnt vmcnt(0)" ::: "memory");
    __builtin_amdgcn_sched_barrier(0);
    *(short8*)Kd0 = kr0;
    *(short8*)Kd1 = kr1;
    *(short8*)Vd0 = vr0;
    *(short8*)Vd1 = vr1;
    // issue next tile's loads: they fly under this tile's compute
    if (kb + 64 < kbend) {
      kr0 = *(const short8*)(Kg0 + (size_t)(kb + 64) * HD);
      kr1 = *(const short8*)(Kg1 + (size_t)(kb + 64) * HD);
      vr0 = *(const short8*)(Vg0 + (kb + 64));
      vr1 = *(const short8*)(Vg1 + (kb + 64));
    }
    // B2: my ds_writes done -> after barrier, all writes visible
    asm volatile("s_waitcnt lgkmcnt(0)" ::: "memory");
    __builtin_amdgcn_sched_barrier(0);
    __builtin_amdgcn_s_barrier();

    // S^T = K·Q^T, p = exp2(s) -> P (bf16) into per-wave LDS
#pragma unroll
    for (int mt = 0; mt < 4; mt++) {
      const int rb = (mt * 16 + l15) * 8;
      short8 a0 = *(const short8*)&Ks[(rb + sw0) * 8];
      short8 a1 = *(const short8*)&Ks[(rb + sw1) * 8];
#pragma unroll
      for (int qnt = 0; qnt < 2; qnt++) {
        float4a s = (float4a){0.f, 0.f, 0.f, 0.f};
        s = __builtin_amdgcn_mfma_f32_16x16x32_bf16(a0, qf[qnt][0], s, 0, 0, 0);
        s = __builtin_amdgcn_mfma_f32_16x16x32_bf16(a1, qf[qnt][1], s, 0, 0, 0);
        uint2 pk;
        pk.x = pack_bf16(__builtin_amdgcn_exp2f(s[0]), __builtin_amdgcn_exp2f(s[1]));
        pk.y = pack_bf16(__builtin_amdgcn_exp2f(s[2]), __builtin_amdgcn_exp2f(s[3]));
        *(uint2*)&Ps[w][qnt * 16 + l15][mt * 16 + quad * 4] = pk;
      }
    }
    asm volatile("s_waitcnt lgkmcnt(0)" ::: "memory");  // P write->read, same wave

    // O += P·V ; l += P·1 (MFMA)
#pragma unroll
    for (int c = 0; c < 2; c++) {
      short8 pa0 = *(const short8*)&Ps[w][l15][c * 32 + quad * 8];
      short8 pa1 = *(const short8*)&Ps[w][16 + l15][c * 32 + quad * 8];
      Lacc[0] = __builtin_amdgcn_mfma_f32_16x16x32_bf16(pa0, ones, Lacc[0], 0, 0, 0);
      Lacc[1] = __builtin_amdgcn_mfma_f32_16x16x32_bf16(pa1, ones, Lacc[1], 0, 0, 0);
      const int vsw = (c * 4 + quad + l15) & 7;
#pragma unroll
      for (int nt = 0; nt < 4; nt++) {
        short8 vb = *(const short8*)&Vs[((nt * 16 + l15) * 8 + vsw) * 8];
        Oacc[0][nt] = __builtin_amdgcn_mfma_f32_16x16x32_bf16(pa0, vb, Oacc[0][nt], 0, 0, 0);
        Oacc[1][nt] = __builtin_amdgcn_mfma_f32_16x16x32_bf16(pa1, vb, Oacc[1][nt], 0, 0, 0);
      }
    }
  }

  if (l15 == 0) {
#pragma unroll
    for (int qnt = 0; qnt < 2; qnt++)
#pragma unroll
      for (int reg = 0; reg < 4; reg++) {
        const int q = qb * 128 + w * 32 + qnt * 16 + quad * 4 + reg;
        Lp[(size_t)sp * ROWS * NH + ((size_t)bb * S_LEN + q) * NH + h] = Lacc[qnt][reg];
      }
  }

  unsigned short* Ob = Op + (size_t)sp * ROWS * D_MODEL;
#pragma unroll
  for (int qnt = 0; qnt < 2; qnt++) {
#pragma unroll
    for (int reg = 0; reg < 4; reg++) {
      const int q = qb * 128 + w * 32 + qnt * 16 + quad * 4 + reg;
      unsigned short* orow = Ob + ((size_t)bb * S_LEN + q) * D_MODEL + h * HD;
#pragma unroll
      for (int nt = 0; nt < 4; nt++)
        orow[nt * 16 + l15] = f2bf(Oacc[qnt][nt][reg]);
    }
  }
}

extern "C" void kernel_launch(void* const* d_in, const int* in_sizes, int n_in,
                              void* d_out, int out_size, void* d_ws, size_t ws_size,
                              hipStream_t stream) {
  const float* query = (const float*)d_in[0];
  const float* key   = (const float*)d_in[1];
  const float* value = (const float*)d_in[2];
  const float* Wq = (const float*)d_in[3];
  const float* bq = (const float*)d_in[4];
  const float* Wk = (const float*)d_in[5];
  const float* bk = (const float*)d_in[6];
  const float* Wv = (const float*)d_in[7];
  const float* bv = (const float*)d_in[8];
  const float* Wo = (const float*)d_in[9];
  const float* bo = (const float*)d_in[10];
  float* out = (float*)d_out;

  char* ws = (char*)d_ws;
  const size_t MB = 1024 * 1024;
  unsigned short* xq16 = (unsigned short*)(ws + 0 * MB);
  unsigned short* xk16 = (unsigned short*)(ws + 8 * MB);
  unsigned short* xv16 = (unsigned short*)(ws + 16 * MB);
  unsigned short* wq16 = (unsigned short*)(ws + 24 * MB);
  unsigned short* wk16 = (unsigned short*)(ws + 26 * MB);
  unsigned short* wv16 = (unsigned short*)(ws + 28 * MB);
  unsigned short* qbuf  = (unsigned short*)(ws + 32 * MB);
  unsigned short* kbuf  = (unsigned short*)(ws + 40 * MB);
  unsigned short* vtbuf = (unsigned short*)(ws + 48 * MB);
  unsigned short* wo16  = (unsigned short*)(ws + 56 * MB);
  float* Lp = (float*)(ws + 58 * MB);
  unsigned short* Op = (unsigned short*)(ws + 0 * MB);  // 2 x 8 MB bf16 partials (aliases dead x)

  ConvArgs ca;
  const int NX = ROWS * D_MODEL, NW = D_MODEL * D_MODEL;
  ca.s[0] = query; ca.d[0] = xq16; ca.n[0] = NX;
  ca.s[1] = key;   ca.d[1] = xk16; ca.n[1] = NX;
  ca.s[2] = value; ca.d[2] = xv16; ca.n[2] = NX;
  ca.s[3] = Wq;    ca.d[3] = wq16; ca.n[3] = NW;
  ca.s[4] = Wk;    ca.d[4] = wk16; ca.n[4] = NW;
  ca.s[5] = Wv;    ca.d[5] = wv16; ca.n[5] = NW;
  ca.s[6] = Wo;    ca.d[6] = wo16; ca.n[6] = NW;
  hipLaunchKernelGGL(convert_bf16, dim3(NX / 2048, 7), dim3(256), 0, stream, ca);

  dim3 gqkv(ROWS / 128, D_MODEL / 128, 3);  // 768 blocks
  hipLaunchKernelGGL(gemm_qkv, gqkv, dim3(256), 0, stream,
                     xq16, xk16, xv16, wq16, wk16, wv16, bq, bk, bv,
                     qbuf, kbuf, vtbuf);

  hipLaunchKernelGGL(attn_kernel, dim3(1024), dim3(256), 0, stream,
                     qbuf, kbuf, vtbuf, Op, Lp);

  dim3 go(ROWS / 64, D_MODEL / 128);        // 512 blocks
  hipLaunchKernelGGL(gemm_o, go, dim3(256), 0, stream, Op, Lp, wo16, bo, out);
}

// Round 5
// 232.348 us; speedup vs baseline: 1.0212x; 1.0212x over previous
//
#include <hip/hip_runtime.h>
#include <hip/hip_bf16.h>

// MHA: B=2, S=2048, D=1024, H=16, hd=64, fp32 in/out.
// Round 12: GEMMs BK 32->64 (halves the 2-barrier vmcnt-drain count; the
//           drain cost scales with iteration count, not bytes). 8-slot LDS
//           swizzle (uniform 8 lanes / 4-bank group = b128 floor). qkv LDS
//           16->32 KB (grid-capped 3 blocks/CU, not binding); gemm_o 12->24KB.
//           attn byte-identical to round 11 (T14 staging, 57.7 us; VALU floor
//           = exp2 27us measured==theory).

constexpr int D_MODEL = 1024;
constexpr int S_LEN   = 2048;
constexpr int BATCH   = 2;
constexpr int NH      = 16;
constexpr int HD      = 64;
constexpr int ROWS    = BATCH * S_LEN;  // 4096

typedef __attribute__((ext_vector_type(8))) short short8;
typedef __attribute__((ext_vector_type(4))) float float4a;

static __device__ __forceinline__ unsigned short f2bf(float f) {
  union { float f; unsigned u; } v{f};
  unsigned r = v.u + 0x7FFFu + ((v.u >> 16) & 1u);  // RNE
  return (unsigned short)(r >> 16);
}

static __device__ __forceinline__ unsigned pack_bf16(float a, float b) {
#if __has_builtin(__builtin_amdgcn_cvt_pk_bf16_f32)
  typedef __attribute__((ext_vector_type(2))) __bf16 bf16x2;
  union { bf16x2 v; unsigned u; } c;
  c.v = __builtin_amdgcn_cvt_pk_bf16_f32(a, b);
  return c.u;
#else
  return (unsigned)f2bf(a) | ((unsigned)f2bf(b) << 16);
#endif
}

static __device__ __forceinline__ float bf2f(unsigned short u) {
  union { unsigned u; float f; } v;
  v.u = (unsigned)u << 16;
  return v.f;
}

// async 16B/lane global -> LDS
static __device__ __forceinline__ void async16(const void* g, void* l) {
  __builtin_amdgcn_global_load_lds(
      (const __attribute__((address_space(1))) unsigned int*)g,
      (__attribute__((address_space(3))) unsigned int*)l, 16, 0, 0);
}

// ---------------- fp32 -> bf16 convert ----------------
struct ConvArgs { const float* s[7]; unsigned short* d[7]; int n[7]; };

__global__ __launch_bounds__(256) void convert_bf16(ConvArgs a) {
  const int which = blockIdx.y;
  const int i = (blockIdx.x * 256 + threadIdx.x) * 8;
  if (i >= a.n[which]) return;
  const float4* s = (const float4*)(a.s[which] + i);
  float4 x = s[0], y = s[1];
  unsigned t[4] = {pack_bf16(x.x, x.y), pack_bf16(x.z, x.w),
                   pack_bf16(y.x, y.y), pack_bf16(y.z, y.w)};
  *(short8*)(a.d[which] + i) = *(short8*)t;
}

// ---------------- MFMA bf16 GEMM: Y = A @ W^T (+bias) ----------------
// 128x128 block tile, BK=64, single-buffer DMA staging (32 KB LDS).
// LDS slot swizzle: slot(r,c) = (c + (r>>1)) & 7  (16B chunks, 8/row).
// MODE 0: bf16 head-major [B,H,S,64], value = (acc + bias)*scale
// MODE 2: bf16 V^T [B,H,64,S] (two-pass per-wave LDS transpose, Tb aliased)
template <int MODE>
static __device__ __forceinline__ void gemm_body(
    const unsigned short* __restrict__ A, const unsigned short* __restrict__ W,
    const float* __restrict__ bias, void* __restrict__ Yv, float scale,
    unsigned short* As, unsigned short* Bs, unsigned short* Tb) {
  const int tid = threadIdx.x;
  const int w = tid >> 6, lane = tid & 63;
  const int l15 = lane & 15, quad = lane >> 4;
  const int row0 = blockIdx.x * 128, col0 = blockIdx.y * 128;
  const int wm = (w & 1) * 64, wn = (w >> 1) * 64;

  float4a acc[4][4];
#pragma unroll
  for (int i = 0; i < 4; i++)
#pragma unroll
    for (int j = 0; j < 4; j++) acc[i][j] = (float4a){0.f, 0.f, 0.f, 0.f};

  for (int kt = 0; kt < D_MODEL; kt += 64) {
    __syncthreads();  // prior ds_reads done before DMA overwrite
#pragma unroll
    for (int j = 0; j < 4; j++) {
      const int i = w * 4 + j;                 // 1KB block: 8 rows x 8 slots
      const int r = i * 8 + (lane >> 3);
      const int c = ((lane & 7) - (r >> 1)) & 7;
      async16(W + (size_t)(col0 + r) * D_MODEL + kt + c * 8, (char*)Bs + i * 1024);
      async16(A + (size_t)(row0 + r) * D_MODEL + kt + c * 8, (char*)As + i * 1024);
    }
    __syncthreads();  // drain vmcnt -> tiles resident

#pragma unroll
    for (int kk = 0; kk < 2; kk++) {
      // (r>>1)&7 == (l15>>1) for r = wm/wn + mt*16 + l15 (wm,wn ≡ 0 mod 64)
      const int sw = (kk * 4 + quad + (l15 >> 1)) & 7;
      short8 af[4], bf[4];
#pragma unroll
      for (int mt = 0; mt < 4; mt++) {
        const int r = wm + mt * 16 + l15;
        af[mt] = *(const short8*)&As[(r * 8 + sw) * 8];
      }
#pragma unroll
      for (int nt = 0; nt < 4; nt++) {
        const int r = wn + nt * 16 + l15;
        bf[nt] = *(const short8*)&Bs[(r * 8 + sw) * 8];
      }
#pragma unroll
      for (int mt = 0; mt < 4; mt++)
#pragma unroll
        for (int nt = 0; nt < 4; nt++)
          acc[mt][nt] = __builtin_amdgcn_mfma_f32_16x16x32_bf16(af[mt], bf[nt], acc[mt][nt], 0, 0, 0);
    }
  }

  int cols[4];
  float bvs[4];
#pragma unroll
  for (int nt = 0; nt < 4; nt++) {
    cols[nt] = col0 + wn + nt * 16 + l15;
    bvs[nt]  = bias[cols[nt]] * ((MODE == 0) ? scale : 1.0f);
  }

  if constexpr (MODE == 0) {
    unsigned short* Y = (unsigned short*)Yv;
#pragma unroll
    for (int mt = 0; mt < 4; mt++)
#pragma unroll
      for (int r = 0; r < 4; r++) {
        const int m = row0 + wm + mt * 16 + quad * 4 + r;
        const int bb = m >> 11, s = m & 2047;
#pragma unroll
        for (int nt = 0; nt < 4; nt++) {
          const int h = cols[nt] >> 6, d = cols[nt] & 63;
          Y[(((size_t)(bb * NH + h)) * S_LEN + s) * HD + d] =
              f2bf(acc[mt][nt][r] * scale + bvs[nt]);
        }
      }
  } else {  // MODE 2: V^T, two-pass per-wave 64x32 transpose (Tb aliases staging)
    __syncthreads();  // all waves' K-loop LDS reads done before alias overwrite
    unsigned short* T = Tb + w * (64 * 32);  // 4 KB per wave
    unsigned short* Y = (unsigned short*)Yv;
#pragma unroll
    for (int p = 0; p < 2; p++) {
      if (p) { asm volatile("s_waitcnt lgkmcnt(0)" ::: "memory"); }  // pass-0 reads retired
#pragma unroll
      for (int mi = 0; mi < 2; mi++) {
        const int mt = 2 * p + mi;
#pragma unroll
        for (int r = 0; r < 4; r++) {
          const int sl = mi * 16 + quad * 4 + r;  // 0..31 within pass
          const int cch = sl >> 3;
#pragma unroll
          for (int nt = 0; nt < 4; nt++) {
            const int dl = nt * 16 + l15;
            const int slot = cch ^ (dl & 3);
            T[dl * 32 + slot * 8 + (sl & 7)] = f2bf(acc[mt][nt][r] + bvs[nt]);
          }
        }
      }
      asm volatile("s_waitcnt lgkmcnt(0)" ::: "memory");  // per-wave write->read
#pragma unroll
      for (int j = 0; j < 4; j++) {
        const int cid = j * 64 + lane;
        const int dl = cid >> 2;   // 0..63
        const int c  = cid & 3;    // s-chunk within pass
        const int slot = c ^ (dl & 3);
        short8 v = *(const short8*)&T[dl * 32 + slot * 8];
        const int col = col0 + wn + dl;
        const int h = col >> 6, d = col & 63;
        const int m = row0 + wm + p * 32 + c * 8;
        const int bb = m >> 11, s = m & 2047;
        *(short8*)&Y[(((size_t)(bb * NH + h)) * HD + d) * S_LEN + s] = v;
      }
    }
  }
}

__global__ __launch_bounds__(256) void gemm_qkv(
    const unsigned short* xq, const unsigned short* xk, const unsigned short* xv,
    const unsigned short* wq, const unsigned short* wk, const unsigned short* wv,
    const float* bq, const float* bk, const float* bv,
    unsigned short* Q, unsigned short* K, unsigned short* Vt) {
  __shared__ unsigned short smem[2 * 128 * 64];  // 32 KB: As + Bs; Tb aliases
  unsigned short* As = smem;
  unsigned short* Bs = smem + 128 * 64;
  unsigned short* Tb = smem;
  const int z = blockIdx.z;
  // Q scale: 1/sqrt(64) * log2(e)  (softmax in exp2 domain)
  if (z == 0)      gemm_body<0>(xq, wq, bq, Q,  0.125f * 1.44269504f, As, Bs, Tb);
  else if (z == 1) gemm_body<0>(xk, wk, bk, K,  1.0f, As, Bs, Tb);
  else             gemm_body<2>(xv, wv, bv, Vt, 1.0f, As, Bs, Tb);
}

// ---------------- gemm_o with fused split-K merge ----------------
// out = ((O0+O1) * 1/(l0+l1)) @ Wo^T + bo.  64x128 tile, BK=64.
// A tile built in registers from bf16 partials (merge fused); W via DMA.
// BK=64 == one head per K-iter -> single rinv per iter.
__global__ __launch_bounds__(256) void gemm_o(
    const unsigned short* __restrict__ Op, const float* __restrict__ Lp,
    const unsigned short* __restrict__ wo, const float* __restrict__ bo,
    float* __restrict__ out) {
  __shared__ unsigned short As[64 * 64];    // 8 KB (8 slots/row)
  __shared__ unsigned short Bs[128 * 64];   // 16 KB
  const int tid = threadIdx.x;
  const int w = tid >> 6, lane = tid & 63;
  const int l15 = lane & 15, quad = lane >> 4;
  const int row0 = blockIdx.x * 64, col0 = blockIdx.y * 128;
  const int wn = w * 32;

  // A-merge path: lane owns row ar, global k-chunks cg and cg+4 (8 bf16 each)
  const int ar = w * 16 + (lane >> 2);
  const int cg = lane & 3;
  const int asl0 = (cg + (ar >> 1)) & 7;
  const int asl1 = (cg + 4 + (ar >> 1)) & 7;
  const int grow = row0 + ar;
  const unsigned short* P0 = Op + (size_t)grow * D_MODEL + cg * 8;
  const unsigned short* P1 = P0 + (size_t)ROWS * D_MODEL;
  const float* L0 = Lp + (size_t)grow * NH;
  const float* L1 = L0 + (size_t)ROWS * NH;

  float4a acc[4][2];
#pragma unroll
  for (int i = 0; i < 4; i++)
#pragma unroll
    for (int j = 0; j < 2; j++) acc[i][j] = (float4a){0.f, 0.f, 0.f, 0.f};

  for (int kt = 0; kt < D_MODEL; kt += 64) {
    const int h = kt >> 6;
    const float rinv = 1.0f / (L0[h] + L1[h]);
    short8 a0 = *(const short8*)(P0 + kt);
    short8 a1 = *(const short8*)(P0 + kt + 32);
    short8 b0 = *(const short8*)(P1 + kt);
    short8 b1 = *(const short8*)(P1 + kt + 32);
    unsigned t0[4], t1[4];
#pragma unroll
    for (int i = 0; i < 4; i++) {
      const float u0 = (bf2f((unsigned short)a0[2 * i]) + bf2f((unsigned short)b0[2 * i])) * rinv;
      const float u1 = (bf2f((unsigned short)a0[2 * i + 1]) + bf2f((unsigned short)b0[2 * i + 1])) * rinv;
      t0[i] = pack_bf16(u0, u1);
      const float v0 = (bf2f((unsigned short)a1[2 * i]) + bf2f((unsigned short)b1[2 * i])) * rinv;
      const float v1 = (bf2f((unsigned short)a1[2 * i + 1]) + bf2f((unsigned short)b1[2 * i + 1])) * rinv;
      t1[i] = pack_bf16(v0, v1);
    }
    __syncthreads();  // prior frag reads done before overwrite
    *(short8*)&As[(ar * 8 + asl0) * 8] = *(short8*)t0;
    *(short8*)&As[(ar * 8 + asl1) * 8] = *(short8*)t1;
#pragma unroll
    for (int j = 0; j < 4; j++) {
      const int i = w * 4 + j;
      const int r = i * 8 + (lane >> 3);
      const int c = ((lane & 7) - (r >> 1)) & 7;
      async16(wo + (size_t)(col0 + r) * D_MODEL + kt + c * 8, (char*)Bs + i * 1024);
    }
    __syncthreads();  // drain vmcnt (DMA) + lgkm (ds_write)

#pragma unroll
    for (int kk = 0; kk < 2; kk++) {
      const int sw = (kk * 4 + quad + (l15 >> 1)) & 7;
      short8 af[4], bf[2];
#pragma unroll
      for (int mt = 0; mt < 4; mt++) {
        const int r = mt * 16 + l15;
        af[mt] = *(const short8*)&As[(r * 8 + sw) * 8];
      }
#pragma unroll
      for (int nt = 0; nt < 2; nt++) {
        const int r = wn + nt * 16 + l15;
        bf[nt] = *(const short8*)&Bs[(r * 8 + sw) * 8];
      }
#pragma unroll
      for (int mt = 0; mt < 4; mt++)
#pragma unroll
        for (int nt = 0; nt < 2; nt++)
          acc[mt][nt] = __builtin_amdgcn_mfma_f32_16x16x32_bf16(af[mt], bf[nt], acc[mt][nt], 0, 0, 0);
    }
  }

#pragma unroll
  for (int nt = 0; nt < 2; nt++) {
    const int col = col0 + wn + nt * 16 + l15;
    const float bv = bo[col];
#pragma unroll
    for (int mt = 0; mt < 4; mt++)
#pragma unroll
      for (int r = 0; r < 4; r++) {
        const int m = row0 + mt * 16 + quad * 4 + r;
        out[(size_t)m * D_MODEL + col] = acc[mt][nt][r] + bv;
      }
  }
}

// ---------------- Flash attention, split-K x2, T14 async-STAGE ----------------
// Per KV-tile (KVBLK=64): next-tile K/V global->reg loads are issued under the
// CURRENT tile's compute; ds_write happens after B1 (all waves' reads done).
// Raw s_barrier + explicit waitcnt so barriers do NOT drain in-flight loads
// (unlike __syncthreads). LDS 34816 B -> 4 blocks/CU.
__global__ __launch_bounds__(256) void attn_kernel(
    const unsigned short* __restrict__ Qh, const unsigned short* __restrict__ Kh,
    const unsigned short* __restrict__ Vt, unsigned short* __restrict__ Op,
    float* __restrict__ Lp) {
  // grid = 1024 (1D). n&7 = XCD; 8 groups/XCD x 16 qb blocks = 128 blocks/XCD.
  const int n   = blockIdx.x;
  const int idx = n >> 3;
  const int qb  = idx & 15;
  const int g   = (n & 7) + 8 * (idx >> 4);  // 0..63
  const int h   = g & 15;
  const int z   = g >> 4;                    // 0..3
  const int bb  = z >> 1, sp = z & 1;

  const int tid = threadIdx.x;
  const int w = tid >> 6, lane = tid & 63;
  const int l15 = lane & 15, quad = lane >> 4;

  __shared__ unsigned short Ks[64 * 64];   // slot(r,c)=r*8+((c+r)&7), 16B chunks
  __shared__ unsigned short Vs[64 * 64];
  __shared__ unsigned short Ps[4][32][72];

  const size_t bh = (size_t)(bb * NH + h);
  const unsigned short* Qp = Qh + bh * S_LEN * HD;
  const unsigned short* Kp = Kh + bh * S_LEN * HD;
  const unsigned short* Vp = Vt + bh * (size_t)HD * S_LEN;

  // staging geometry (identical layout to the old DMA path):
  // chunk j in {0,1}: i = w*2+j, r = i*8 + (lane>>3), c = ((lane&7) - r) & 7
  // LDS dst = base + i*1024 + lane*16;  r1 = r0+8 -> same c.
  const int r0 = w * 16 + (lane >> 3);
  const int c0 = ((lane & 7) - r0) & 7;
  const unsigned short* Kg0 = Kp + (size_t)r0 * HD + c0 * 8;
  const unsigned short* Kg1 = Kg0 + 8 * HD;
  const unsigned short* Vg0 = Vp + (size_t)r0 * S_LEN + c0 * 8;
  const unsigned short* Vg1 = Vg0 + 8 * S_LEN;
  unsigned short* Kd0 = (unsigned short*)((char*)Ks + (w * 2) * 1024 + (size_t)lane * 16);
  unsigned short* Kd1 = (unsigned short*)((char*)Kd0 + 1024);
  unsigned short* Vd0 = (unsigned short*)((char*)Vs + (w * 2) * 1024 + (size_t)lane * 16);
  unsigned short* Vd1 = (unsigned short*)((char*)Vd0 + 1024);

  short8 qf[2][2];
#pragma unroll
  for (int qnt = 0; qnt < 2; qnt++)
#pragma unroll
    for (int c = 0; c < 2; c++)
      qf[qnt][c] = *(const short8*)(Qp + (size_t)(qb * 128 + w * 32 + qnt * 16 + l15) * HD +
                                    c * 32 + quad * 8);

  unsigned short ob[8] = {0x3F80, 0x3F80, 0x3F80, 0x3F80, 0x3F80, 0x3F80, 0x3F80, 0x3F80};
  const short8 ones = *(short8*)ob;

  float4a Oacc[2][4];
#pragma unroll
  for (int a = 0; a < 2; a++)
#pragma unroll
    for (int b = 0; b < 4; b++) Oacc[a][b] = (float4a){0.f, 0.f, 0.f, 0.f};
  float4a Lacc[2] = {(float4a){0.f, 0.f, 0.f, 0.f}, (float4a){0.f, 0.f, 0.f, 0.f}};

  const int sw0 = (quad + l15) & 7;
  const int sw1 = (quad + 4 + l15) & 7;

  const int kb0 = sp * 1024, kbend = kb0 + 1024;

  // prologue: stage tile 0 into regs
  short8 kr0 = *(const short8*)(Kg0 + (size_t)kb0 * HD);
  short8 kr1 = *(const short8*)(Kg1 + (size_t)kb0 * HD);
  short8 vr0 = *(const short8*)(Vg0 + kb0);
  short8 vr1 = *(const short8*)(Vg1 + kb0);

  for (int kb = kb0; kb < kbend; kb += 64) {
    // B1: all waves' LDS reads of the previous tile retired
    asm volatile("s_waitcnt lgkmcnt(0)" ::: "memory");
    __builtin_amdgcn_sched_barrier(0);
    __builtin_amdgcn_s_barrier();
    // staged data arrived (loads were issued one full compute phase ago)
    asm volatile("s_waitcnt vmcnt(0)" ::: "memory");
    __builtin_amdgcn_sched_barrier(0);
    *(short8*)Kd0 = kr0;
    *(short8*)Kd1 = kr1;
    *(short8*)Vd0 = vr0;
    *(short8*)Vd1 = vr1;
    // issue next tile's loads: they fly under this tile's compute
    if (kb + 64 < kbend) {
      kr0 = *(const short8*)(Kg0 + (size_t)(kb + 64) * HD);
      kr1 = *(const short8*)(Kg1 + (size_t)(kb + 64) * HD);
      vr0 = *(const short8*)(Vg0 + (kb + 64));
      vr1 = *(const short8*)(Vg1 + (kb + 64));
    }
    // B2: my ds_writes done -> after barrier, all writes visible
    asm volatile("s_waitcnt lgkmcnt(0)" ::: "memory");
    __builtin_amdgcn_sched_barrier(0);
    __builtin_amdgcn_s_barrier();

    // S^T = K·Q^T, p = exp2(s) -> P (bf16) into per-wave LDS
#pragma unroll
    for (int mt = 0; mt < 4; mt++) {
      const int rb = (mt * 16 + l15) * 8;
      short8 a0 = *(const short8*)&Ks[(rb + sw0) * 8];
      short8 a1 = *(const short8*)&Ks[(rb + sw1) * 8];
#pragma unroll
      for (int qnt = 0; qnt < 2; qnt++) {
        float4a s = (float4a){0.f, 0.f, 0.f, 0.f};
        s = __builtin_amdgcn_mfma_f32_16x16x32_bf16(a0, qf[qnt][0], s, 0, 0, 0);
        s = __builtin_amdgcn_mfma_f32_16x16x32_bf16(a1, qf[qnt][1], s, 0, 0, 0);
        uint2 pk;
        pk.x = pack_bf16(__builtin_amdgcn_exp2f(s[0]), __builtin_amdgcn_exp2f(s[1]));
        pk.y = pack_bf16(__builtin_amdgcn_exp2f(s[2]), __builtin_amdgcn_exp2f(s[3]));
        *(uint2*)&Ps[w][qnt * 16 + l15][mt * 16 + quad * 4] = pk;
      }
    }
    asm volatile("s_waitcnt lgkmcnt(0)" ::: "memory");  // P write->read, same wave

    // O += P·V ; l += P·1 (MFMA)
#pragma unroll
    for (int c = 0; c < 2; c++) {
      short8 pa0 = *(const short8*)&Ps[w][l15][c * 32 + quad * 8];
      short8 pa1 = *(const short8*)&Ps[w][16 + l15][c * 32 + quad * 8];
      Lacc[0] = __builtin_amdgcn_mfma_f32_16x16x32_bf16(pa0, ones, Lacc[0], 0, 0, 0);
      Lacc[1] = __builtin_amdgcn_mfma_f32_16x16x32_bf16(pa1, ones, Lacc[1], 0, 0, 0);
      const int vsw = (c * 4 + quad + l15) & 7;
#pragma unroll
      for (int nt = 0; nt < 4; nt++) {
        short8 vb = *(const short8*)&Vs[((nt * 16 + l15) * 8 + vsw) * 8];
        Oacc[0][nt] = __builtin_amdgcn_mfma_f32_16x16x32_bf16(pa0, vb, Oacc[0][nt], 0, 0, 0);
        Oacc[1][nt] = __builtin_amdgcn_mfma_f32_16x16x32_bf16(pa1, vb, Oacc[1][nt], 0, 0, 0);
      }
    }
  }

  if (l15 == 0) {
#pragma unroll
    for (int qnt = 0; qnt < 2; qnt++)
#pragma unroll
      for (int reg = 0; reg < 4; reg++) {
        const int q = qb * 128 + w * 32 + qnt * 16 + quad * 4 + reg;
        Lp[(size_t)sp * ROWS * NH + ((size_t)bb * S_LEN + q) * NH + h] = Lacc[qnt][reg];
      }
  }

  unsigned short* Ob = Op + (size_t)sp * ROWS * D_MODEL;
#pragma unroll
  for (int qnt = 0; qnt < 2; qnt++) {
#pragma unroll
    for (int reg = 0; reg < 4; reg++) {
      const int q = qb * 128 + w * 32 + qnt * 16 + quad * 4 + reg;
      unsigned short* orow = Ob + ((size_t)bb * S_LEN + q) * D_MODEL + h * HD;
#pragma unroll
      for (int nt = 0; nt < 4; nt++)
        orow[nt * 16 + l15] = f2bf(Oacc[qnt][nt][reg]);
    }
  }
}

extern "C" void kernel_launch(void* const* d_in, const int* in_sizes, int n_in,
                              void* d_out, int out_size, void* d_ws, size_t ws_size,
                              hipStream_t stream) {
  const float* query = (const float*)d_in[0];
  const float* key   = (const float*)d_in[1];
  const float* value = (const float*)d_in[2];
  const float* Wq = (const float*)d_in[3];
  const float* bq = (const float*)d_in[4];
  const float* Wk = (const float*)d_in[5];
  const float* bk = (const float*)d_in[6];
  const float* Wv = (const float*)d_in[7];
  const float* bv = (const float*)d_in[8];
  const float* Wo = (const float*)d_in[9];
  const float* bo = (const float*)d_in[10];
  float* out = (float*)d_out;

  char* ws = (char*)d_ws;
  const size_t MB = 1024 * 1024;
  unsigned short* xq16 = (unsigned short*)(ws + 0 * MB);
  unsigned short* xk16 = (unsigned short*)(ws + 8 * MB);
  unsigned short* xv16 = (unsigned short*)(ws + 16 * MB);
  unsigned short* wq16 = (unsigned short*)(ws + 24 * MB);
  unsigned short* wk16 = (unsigned short*)(ws + 26 * MB);
  unsigned short* wv16 = (unsigned short*)(ws + 28 * MB);
  unsigned short* qbuf  = (unsigned short*)(ws + 32 * MB);
  unsigned short* kbuf  = (unsigned short*)(ws + 40 * MB);
  unsigned short* vtbuf = (unsigned short*)(ws + 48 * MB);
  unsigned short* wo16  = (unsigned short*)(ws + 56 * MB);
  float* Lp = (float*)(ws + 58 * MB);
  unsigned short* Op = (unsigned short*)(ws + 0 * MB);  // 2 x 8 MB bf16 partials (aliases dead x)

  ConvArgs ca;
  const int NX = ROWS * D_MODEL, NW = D_MODEL * D_MODEL;
  ca.s[0] = query; ca.d[0] = xq16; ca.n[0] = NX;
  ca.s[1] = key;   ca.d[1] = xk16; ca.n[1] = NX;
  ca.s[2] = value; ca.d[2] = xv16; ca.n[2] = NX;
  ca.s[3] = Wq;    ca.d[3] = wq16; ca.n[3] = NW;
  ca.s[4] = Wk;    ca.d[4] = wk16; ca.n[4] = NW;
  ca.s[5] = Wv;    ca.d[5] = wv16; ca.n[5] = NW;
  ca.s[6] = Wo;    ca.d[6] = wo16; ca.n[6] = NW;
  hipLaunchKernelGGL(convert_bf16, dim3(NX / 2048, 7), dim3(256), 0, stream, ca);

  dim3 gqkv(ROWS / 128, D_MODEL / 128, 3);  // 768 blocks
  hipLaunchKernelGGL(gemm_qkv, gqkv, dim3(256), 0, stream,
                     xq16, xk16, xv16, wq16, wk16, wv16, bq, bk, bv,
                     qbuf, kbuf, vtbuf);

  hipLaunchKernelGGL(attn_kernel, dim3(1024), dim3(256), 0, stream,
                     qbuf, kbuf, vtbuf, Op, Lp);

  dim3 go(ROWS / 64, D_MODEL / 128);        // 512 blocks
  hipLaunchKernelGGL(gemm_o, go, dim3(256), 0, stream, Op, Lp, wo16, bo, out);
}

// Round 6
// 232.024 us; speedup vs baseline: 1.0226x; 1.0014x over previous
//
#include <hip/hip_runtime.h>
#include <hip/hip_bf16.h>

// MHA: B=2, S=2048, D=1024, H=16, hd=64, fp32 in/out.
// Round 13: GEMM K-loops restructured so every load is covered by a full
//           compute phase (attn round-11 T14 pattern, verified): A reg-staged
//           (issued prev stage), W LDS-double-buffered via DMA (issued prev
//           compute start), single vmcnt(0)/iter with raw s_barrier pairs.
//           x fp32->bf16 convert FUSED into gemm_qkv A-staging (cvt_pk, bit-
//           identical); convert kernel now weights-only (~25 MB traffic).
//           qkv LDS 48 KB (3 blocks/CU), gemm_o 40 KB (2 blocks/CU).
//           attn byte-identical to round 12 (56.4 us; at exp2 VALU floor).

constexpr int D_MODEL = 1024;
constexpr int S_LEN   = 2048;
constexpr int BATCH   = 2;
constexpr int NH      = 16;
constexpr int HD      = 64;
constexpr int ROWS    = BATCH * S_LEN;  // 4096

typedef __attribute__((ext_vector_type(8))) short short8;
typedef __attribute__((ext_vector_type(4))) float float4a;

static __device__ __forceinline__ unsigned short f2bf(float f) {
  union { float f; unsigned u; } v{f};
  unsigned r = v.u + 0x7FFFu + ((v.u >> 16) & 1u);  // RNE
  return (unsigned short)(r >> 16);
}

static __device__ __forceinline__ unsigned pack_bf16(float a, float b) {
#if __has_builtin(__builtin_amdgcn_cvt_pk_bf16_f32)
  typedef __attribute__((ext_vector_type(2))) __bf16 bf16x2;
  union { bf16x2 v; unsigned u; } c;
  c.v = __builtin_amdgcn_cvt_pk_bf16_f32(a, b);
  return c.u;
#else
  return (unsigned)f2bf(a) | ((unsigned)f2bf(b) << 16);
#endif
}

static __device__ __forceinline__ float bf2f(unsigned short u) {
  union { unsigned u; float f; } v;
  v.u = (unsigned)u << 16;
  return v.f;
}

// async 16B/lane global -> LDS
static __device__ __forceinline__ void async16(const void* g, void* l) {
  __builtin_amdgcn_global_load_lds(
      (const __attribute__((address_space(1))) unsigned int*)g,
      (__attribute__((address_space(3))) unsigned int*)l, 16, 0, 0);
}

#define WAIT_LGKM0_SB() do { \
  asm volatile("s_waitcnt lgkmcnt(0)" ::: "memory"); \
  __builtin_amdgcn_sched_barrier(0); } while (0)
#define WAIT_VM0_SB() do { \
  asm volatile("s_waitcnt vmcnt(0)" ::: "memory"); \
  __builtin_amdgcn_sched_barrier(0); } while (0)
#define BARRIER_SB() do { \
  __builtin_amdgcn_s_barrier(); \
  __builtin_amdgcn_sched_barrier(0); } while (0)

// ---------------- fp32 -> bf16 convert (weights only) ----------------
struct ConvArgs { const float* s[4]; unsigned short* d[4]; int n[4]; };

__global__ __launch_bounds__(256) void convert_bf16(ConvArgs a) {
  const int which = blockIdx.y;
  const int i = (blockIdx.x * 256 + threadIdx.x) * 8;
  if (i >= a.n[which]) return;
  const float4* s = (const float4*)(a.s[which] + i);
  float4 x = s[0], y = s[1];
  unsigned t[4] = {pack_bf16(x.x, x.y), pack_bf16(x.z, x.w),
                   pack_bf16(y.x, y.y), pack_bf16(y.z, y.w)};
  *(short8*)(a.d[which] + i) = *(short8*)t;
}

// ---------------- MFMA bf16 GEMM: Y = (fp32 A) @ W^T (+bias) ----------------
// 128x128 tile, BK=64. A: fp32 global -> regs (issued prev stage) -> cvt_pk ->
// LDS (16 KB). W: bf16 DMA into double-buffered LDS (2x16 KB), issued at prev
// compute start. One vmcnt(0)/iter, fully covered. Slot swizzle
// slot(r,c) = (c + (r>>1)) & 7 (16B chunks, 8/row).
// MODE 0: bf16 head-major [B,H,S,64], value = (acc + bias)*scale
// MODE 2: bf16 V^T [B,H,64,S] (two-pass per-wave LDS transpose, Tb aliased)
template <int MODE>
static __device__ __forceinline__ void gemm_body(
    const float* __restrict__ A, const unsigned short* __restrict__ W,
    const float* __restrict__ bias, void* __restrict__ Yv, float scale,
    unsigned short* As, unsigned short* Bsb, unsigned short* Tb) {
  const int tid = threadIdx.x;
  const int w = tid >> 6, lane = tid & 63;
  const int l15 = lane & 15, quad = lane >> 4;
  const int row0 = blockIdx.x * 128, col0 = blockIdx.y * 128;
  const int wm = (w & 1) * 64, wn = (w >> 1) * 64;

  // staging geometry: chunk j -> 1KB block i=w*4+j, row r=i*8+(lane>>3),
  // source chunk c = ((lane&7) - (r>>1)) & 7 lands in slot lane&7.
  int rA[4], cA[4];
#pragma unroll
  for (int j = 0; j < 4; j++) {
    const int i = w * 4 + j;
    rA[j] = i * 8 + (lane >> 3);
    cA[j] = ((lane & 7) - (rA[j] >> 1)) & 7;
  }

  float4 av[4][2];
  auto loadA = [&](int kt) {
#pragma unroll
    for (int j = 0; j < 4; j++) {
      const float* s = A + (size_t)(row0 + rA[j]) * D_MODEL + kt + cA[j] * 8;
      av[j][0] = *(const float4*)s;
      av[j][1] = *(const float4*)(s + 4);
    }
  };
  auto loadW = [&](int kt, unsigned short* Bdst) {
#pragma unroll
    for (int j = 0; j < 4; j++) {
      const int i = w * 4 + j;
      async16(W + (size_t)(col0 + rA[j]) * D_MODEL + kt + cA[j] * 8,
              (char*)Bdst + i * 1024);
    }
  };

  float4a acc[4][4];
#pragma unroll
  for (int i = 0; i < 4; i++)
#pragma unroll
    for (int j = 0; j < 4; j++) acc[i][j] = (float4a){0.f, 0.f, 0.f, 0.f};

  // prologue: tile 0 in flight (exposed once)
  loadA(0);
  loadW(0, Bsb);

  for (int kt = 0; kt < D_MODEL; kt += 64) {
    const int cur = (kt >> 6) & 1;
    unsigned short* Bc = Bsb + cur * (128 * 64);
    unsigned short* Bn = Bsb + (cur ^ 1) * (128 * 64);
    const bool more = (kt + 64 < D_MODEL);

    // B1: all waves' LDS reads of prev tile retired
    WAIT_LGKM0_SB();
    BARRIER_SB();
    // my A(kt) regs + W(kt) DMA landed (issued >= one compute phase ago)
    WAIT_VM0_SB();
    // A: cvt + ds_write
#pragma unroll
    for (int j = 0; j < 4; j++) {
      unsigned t[4] = {pack_bf16(av[j][0].x, av[j][0].y), pack_bf16(av[j][0].z, av[j][0].w),
                       pack_bf16(av[j][1].x, av[j][1].y), pack_bf16(av[j][1].z, av[j][1].w)};
      *(short8*)((char*)As + (w * 4 + j) * 1024 + (size_t)lane * 16) = *(short8*)t;
    }
    if (more) loadA(kt + 64);  // flies under this tile's compute
    // B2: ds_writes visible
    WAIT_LGKM0_SB();
    BARRIER_SB();
    if (more) loadW(kt + 64, Bn);  // flies under this tile's compute

#pragma unroll
    for (int kk = 0; kk < 2; kk++) {
      const int sw = (kk * 4 + quad + (l15 >> 1)) & 7;
      short8 af[4], bf[4];
#pragma unroll
      for (int mt = 0; mt < 4; mt++) {
        const int r = wm + mt * 16 + l15;
        af[mt] = *(const short8*)&As[(r * 8 + sw) * 8];
      }
#pragma unroll
      for (int nt = 0; nt < 4; nt++) {
        const int r = wn + nt * 16 + l15;
        bf[nt] = *(const short8*)&Bc[(r * 8 + sw) * 8];
      }
#pragma unroll
      for (int mt = 0; mt < 4; mt++)
#pragma unroll
        for (int nt = 0; nt < 4; nt++)
          acc[mt][nt] = __builtin_amdgcn_mfma_f32_16x16x32_bf16(af[mt], bf[nt], acc[mt][nt], 0, 0, 0);
    }
  }

  int cols[4];
  float bvs[4];
#pragma unroll
  for (int nt = 0; nt < 4; nt++) {
    cols[nt] = col0 + wn + nt * 16 + l15;
    bvs[nt]  = bias[cols[nt]] * ((MODE == 0) ? scale : 1.0f);
  }

  if constexpr (MODE == 0) {
    unsigned short* Y = (unsigned short*)Yv;
#pragma unroll
    for (int mt = 0; mt < 4; mt++)
#pragma unroll
      for (int r = 0; r < 4; r++) {
        const int m = row0 + wm + mt * 16 + quad * 4 + r;
        const int bb = m >> 11, s = m & 2047;
#pragma unroll
        for (int nt = 0; nt < 4; nt++) {
          const int h = cols[nt] >> 6, d = cols[nt] & 63;
          Y[(((size_t)(bb * NH + h)) * S_LEN + s) * HD + d] =
              f2bf(acc[mt][nt][r] * scale + bvs[nt]);
        }
      }
  } else {  // MODE 2: V^T, two-pass per-wave 64x32 transpose (Tb aliases As)
    __syncthreads();  // all waves' K-loop LDS reads done before alias overwrite
    unsigned short* T = Tb + w * (64 * 32);  // 4 KB per wave
    unsigned short* Y = (unsigned short*)Yv;
#pragma unroll
    for (int p = 0; p < 2; p++) {
      if (p) { asm volatile("s_waitcnt lgkmcnt(0)" ::: "memory"); }  // pass-0 reads retired
#pragma unroll
      for (int mi = 0; mi < 2; mi++) {
        const int mt = 2 * p + mi;
#pragma unroll
        for (int r = 0; r < 4; r++) {
          const int sl = mi * 16 + quad * 4 + r;  // 0..31 within pass
          const int cch = sl >> 3;
#pragma unroll
          for (int nt = 0; nt < 4; nt++) {
            const int dl = nt * 16 + l15;
            const int slot = cch ^ (dl & 3);
            T[dl * 32 + slot * 8 + (sl & 7)] = f2bf(acc[mt][nt][r] + bvs[nt]);
          }
        }
      }
      asm volatile("s_waitcnt lgkmcnt(0)" ::: "memory");  // per-wave write->read
#pragma unroll
      for (int j = 0; j < 4; j++) {
        const int cid = j * 64 + lane;
        const int dl = cid >> 2;   // 0..63
        const int c  = cid & 3;    // s-chunk within pass
        const int slot = c ^ (dl & 3);
        short8 v = *(const short8*)&T[dl * 32 + slot * 8];
        const int col = col0 + wn + dl;
        const int h = col >> 6, d = col & 63;
        const int m = row0 + wm + p * 32 + c * 8;
        const int bb = m >> 11, s = m & 2047;
        *(short8*)&Y[(((size_t)(bb * NH + h)) * HD + d) * S_LEN + s] = v;
      }
    }
  }
}

__global__ __launch_bounds__(256) void gemm_qkv(
    const float* xq, const float* xk, const float* xv,
    const unsigned short* wq, const unsigned short* wk, const unsigned short* wv,
    const float* bq, const float* bk, const float* bv,
    unsigned short* Q, unsigned short* K, unsigned short* Vt) {
  __shared__ unsigned short smem[3 * 128 * 64];  // 48 KB: As(16) + W dbuf(32)
  unsigned short* As  = smem;
  unsigned short* Bsb = smem + 128 * 64;
  unsigned short* Tb  = smem;  // MODE 2 transpose aliases As (first 16 KB)
  const int z = blockIdx.z;
  // Q scale: 1/sqrt(64) * log2(e)  (softmax in exp2 domain)
  if (z == 0)      gemm_body<0>(xq, wq, bq, Q,  0.125f * 1.44269504f, As, Bsb, Tb);
  else if (z == 1) gemm_body<0>(xk, wk, bk, K,  1.0f, As, Bsb, Tb);
  else             gemm_body<2>(xv, wv, bv, Vt, 1.0f, As, Bsb, Tb);
}

// ---------------- gemm_o with fused split-K merge ----------------
// out = ((O0+O1) * 1/(l0+l1)) @ Wo^T + bo.  64x128 tile, BK=64.
// Partials P + L loaded one iter ahead (covered); Wo DMA double-buffered.
__global__ __launch_bounds__(256) void gemm_o(
    const unsigned short* __restrict__ Op, const float* __restrict__ Lp,
    const unsigned short* __restrict__ wo, const float* __restrict__ bo,
    float* __restrict__ out) {
  __shared__ unsigned short As[64 * 64];        // 8 KB (8 slots/row)
  __shared__ unsigned short Bsb[2 * 128 * 64];  // 32 KB dbuf
  const int tid = threadIdx.x;
  const int w = tid >> 6, lane = tid & 63;
  const int l15 = lane & 15, quad = lane >> 4;
  const int row0 = blockIdx.x * 64, col0 = blockIdx.y * 128;
  const int wn = w * 32;

  // A-merge path: lane owns row ar, global k-chunks cg and cg+4 (8 bf16 each)
  const int ar = w * 16 + (lane >> 2);
  const int cg = lane & 3;
  const int asl0 = (cg + (ar >> 1)) & 7;
  const int asl1 = (cg + 4 + (ar >> 1)) & 7;
  const int grow = row0 + ar;
  const unsigned short* P0 = Op + (size_t)grow * D_MODEL + cg * 8;
  const unsigned short* P1 = P0 + (size_t)ROWS * D_MODEL;
  const float* L0 = Lp + (size_t)grow * NH;
  const float* L1 = L0 + (size_t)ROWS * NH;

  // W staging geometry
  int rB[4], cB[4];
#pragma unroll
  for (int j = 0; j < 4; j++) {
    const int i = w * 4 + j;
    rB[j] = i * 8 + (lane >> 3);
    cB[j] = ((lane & 7) - (rB[j] >> 1)) & 7;
  }
  auto loadW = [&](int kt, unsigned short* Bdst) {
#pragma unroll
    for (int j = 0; j < 4; j++) {
      const int i = w * 4 + j;
      async16(wo + (size_t)(col0 + rB[j]) * D_MODEL + kt + cB[j] * 8,
              (char*)Bdst + i * 1024);
    }
  };

  float4a acc[4][2];
#pragma unroll
  for (int i = 0; i < 4; i++)
#pragma unroll
    for (int j = 0; j < 2; j++) acc[i][j] = (float4a){0.f, 0.f, 0.f, 0.f};

  // prologue: tile 0 in flight
  short8 a0 = *(const short8*)(P0 + 0);
  short8 a1 = *(const short8*)(P0 + 32);
  short8 b0 = *(const short8*)(P1 + 0);
  short8 b1 = *(const short8*)(P1 + 32);
  float l0r = L0[0], l1r = L1[0];
  loadW(0, Bsb);

  for (int kt = 0; kt < D_MODEL; kt += 64) {
    const int cur = (kt >> 6) & 1;
    unsigned short* Bc = Bsb + cur * (128 * 64);
    unsigned short* Bn = Bsb + (cur ^ 1) * (128 * 64);
    const bool more = (kt + 64 < D_MODEL);

    // B1: all waves' LDS reads of prev tile retired
    WAIT_LGKM0_SB();
    BARRIER_SB();
    // staged P/L regs + W(kt) DMA landed
    WAIT_VM0_SB();
    {
      const float rinv = 1.0f / (l0r + l1r);
      unsigned t0[4], t1[4];
#pragma unroll
      for (int i = 0; i < 4; i++) {
        const float u0 = (bf2f((unsigned short)a0[2 * i]) + bf2f((unsigned short)b0[2 * i])) * rinv;
        const float u1 = (bf2f((unsigned short)a0[2 * i + 1]) + bf2f((unsigned short)b0[2 * i + 1])) * rinv;
        t0[i] = pack_bf16(u0, u1);
        const float v0 = (bf2f((unsigned short)a1[2 * i]) + bf2f((unsigned short)b1[2 * i])) * rinv;
        const float v1 = (bf2f((unsigned short)a1[2 * i + 1]) + bf2f((unsigned short)b1[2 * i + 1])) * rinv;
        t1[i] = pack_bf16(v0, v1);
      }
      *(short8*)&As[(ar * 8 + asl0) * 8] = *(short8*)t0;
      *(short8*)&As[(ar * 8 + asl1) * 8] = *(short8*)t1;
    }
    if (more) {  // next partials + L fly under this tile's compute
      const int ktn = kt + 64, hn = ktn >> 6;
      a0 = *(const short8*)(P0 + ktn);
      a1 = *(const short8*)(P0 + ktn + 32);
      b0 = *(const short8*)(P1 + ktn);
      b1 = *(const short8*)(P1 + ktn + 32);
      l0r = L0[hn];
      l1r = L1[hn];
    }
    // B2: ds_writes visible
    WAIT_LGKM0_SB();
    BARRIER_SB();
    if (more) loadW(kt + 64, Bn);

#pragma unroll
    for (int kk = 0; kk < 2; kk++) {
      const int sw = (kk * 4 + quad + (l15 >> 1)) & 7;
      short8 af[4], bf[2];
#pragma unroll
      for (int mt = 0; mt < 4; mt++) {
        const int r = mt * 16 + l15;
        af[mt] = *(const short8*)&As[(r * 8 + sw) * 8];
      }
#pragma unroll
      for (int nt = 0; nt < 2; nt++) {
        const int r = wn + nt * 16 + l15;
        bf[nt] = *(const short8*)&Bc[(r * 8 + sw) * 8];
      }
#pragma unroll
      for (int mt = 0; mt < 4; mt++)
#pragma unroll
        for (int nt = 0; nt < 2; nt++)
          acc[mt][nt] = __builtin_amdgcn_mfma_f32_16x16x32_bf16(af[mt], bf[nt], acc[mt][nt], 0, 0, 0);
    }
  }

#pragma unroll
  for (int nt = 0; nt < 2; nt++) {
    const int col = col0 + wn + nt * 16 + l15;
    const float bv = bo[col];
#pragma unroll
    for (int mt = 0; mt < 4; mt++)
#pragma unroll
      for (int r = 0; r < 4; r++) {
        const int m = row0 + mt * 16 + quad * 4 + r;
        out[(size_t)m * D_MODEL + col] = acc[mt][nt][r] + bv;
      }
  }
}

// ---------------- Flash attention, split-K x2, T14 async-STAGE ----------------
// Per KV-tile (KVBLK=64): next-tile K/V global->reg loads are issued under the
// CURRENT tile's compute; ds_write happens after B1 (all waves' reads done).
// Raw s_barrier + explicit waitcnt so barriers do NOT drain in-flight loads
// (unlike __syncthreads). LDS 34816 B -> 4 blocks/CU.
__global__ __launch_bounds__(256) void attn_kernel(
    const unsigned short* __restrict__ Qh, const unsigned short* __restrict__ Kh,
    const unsigned short* __restrict__ Vt, unsigned short* __restrict__ Op,
    float* __restrict__ Lp) {
  // grid = 1024 (1D). n&7 = XCD; 8 groups/XCD x 16 qb blocks = 128 blocks/XCD.
  const int n   = blockIdx.x;
  const int idx = n >> 3;
  const int qb  = idx & 15;
  const int g   = (n & 7) + 8 * (idx >> 4);  // 0..63
  const int h   = g & 15;
  const int z   = g >> 4;                    // 0..3
  const int bb  = z >> 1, sp = z & 1;

  const int tid = threadIdx.x;
  const int w = tid >> 6, lane = tid & 63;
  const int l15 = lane & 15, quad = lane >> 4;

  __shared__ unsigned short Ks[64 * 64];   // slot(r,c)=r*8+((c+r)&7), 16B chunks
  __shared__ unsigned short Vs[64 * 64];
  __shared__ unsigned short Ps[4][32][72];

  const size_t bh = (size_t)(bb * NH + h);
  const unsigned short* Qp = Qh + bh * S_LEN * HD;
  const unsigned short* Kp = Kh + bh * S_LEN * HD;
  const unsigned short* Vp = Vt + bh * (size_t)HD * S_LEN;

  // staging geometry (identical layout to the old DMA path):
  // chunk j in {0,1}: i = w*2+j, r = i*8 + (lane>>3), c = ((lane&7) - r) & 7
  // LDS dst = base + i*1024 + lane*16;  r1 = r0+8 -> same c.
  const int r0 = w * 16 + (lane >> 3);
  const int c0 = ((lane & 7) - r0) & 7;
  const unsigned short* Kg0 = Kp + (size_t)r0 * HD + c0 * 8;
  const unsigned short* Kg1 = Kg0 + 8 * HD;
  const unsigned short* Vg0 = Vp + (size_t)r0 * S_LEN + c0 * 8;
  const unsigned short* Vg1 = Vg0 + 8 * S_LEN;
  unsigned short* Kd0 = (unsigned short*)((char*)Ks + (w * 2) * 1024 + (size_t)lane * 16);
  unsigned short* Kd1 = (unsigned short*)((char*)Kd0 + 1024);
  unsigned short* Vd0 = (unsigned short*)((char*)Vs + (w * 2) * 1024 + (size_t)lane * 16);
  unsigned short* Vd1 = (unsigned short*)((char*)Vd0 + 1024);

  short8 qf[2][2];
#pragma unroll
  for (int qnt = 0; qnt < 2; qnt++)
#pragma unroll
    for (int c = 0; c < 2; c++)
      qf[qnt][c] = *(const short8*)(Qp + (size_t)(qb * 128 + w * 32 + qnt * 16 + l15) * HD +
                                    c * 32 + quad * 8);

  unsigned short ob[8] = {0x3F80, 0x3F80, 0x3F80, 0x3F80, 0x3F80, 0x3F80, 0x3F80, 0x3F80};
  const short8 ones = *(short8*)ob;

  float4a Oacc[2][4];
#pragma unroll
  for (int a = 0; a < 2; a++)
#pragma unroll
    for (int b = 0; b < 4; b++) Oacc[a][b] = (float4a){0.f, 0.f, 0.f, 0.f};
  float4a Lacc[2] = {(float4a){0.f, 0.f, 0.f, 0.f}, (float4a){0.f, 0.f, 0.f, 0.f}};

  const int sw0 = (quad + l15) & 7;
  const int sw1 = (quad + 4 + l15) & 7;

  const int kb0 = sp * 1024, kbend = kb0 + 1024;

  // prologue: stage tile 0 into regs
  short8 kr0 = *(const short8*)(Kg0 + (size_t)kb0 * HD);
  short8 kr1 = *(const short8*)(Kg1 + (size_t)kb0 * HD);
  short8 vr0 = *(const short8*)(Vg0 + kb0);
  short8 vr1 = *(const short8*)(Vg1 + kb0);

  for (int kb = kb0; kb < kbend; kb += 64) {
    // B1: all waves' LDS reads of the previous tile retired
    asm volatile("s_waitcnt lgkmcnt(0)" ::: "memory");
    __builtin_amdgcn_sched_barrier(0);
    __builtin_amdgcn_s_barrier();
    // staged data arrived (loads were issued one full compute phase ago)
    asm volatile("s_waitcnt vmcnt(0)" ::: "memory");
    __builtin_amdgcn_sched_barrier(0);
    *(short8*)Kd0 = kr0;
    *(short8*)Kd1 = kr1;
    *(short8*)Vd0 = vr0;
    *(short8*)Vd1 = vr1;
    // issue next tile's loads: they fly under this tile's compute
    if (kb + 64 < kbend) {
      kr0 = *(const short8*)(Kg0 + (size_t)(kb + 64) * HD);
      kr1 = *(const short8*)(Kg1 + (size_t)(kb + 64) * HD);
      vr0 = *(const short8*)(Vg0 + (kb + 64));
      vr1 = *(const short8*)(Vg1 + (kb + 64));
    }
    // B2: my ds_writes done -> after barrier, all writes visible
    asm volatile("s_waitcnt lgkmcnt(0)" ::: "memory");
    __builtin_amdgcn_sched_barrier(0);
    __builtin_amdgcn_s_barrier();

    // S^T = K·Q^T, p = exp2(s) -> P (bf16) into per-wave LDS
#pragma unroll
    for (int mt = 0; mt < 4; mt++) {
      const int rb = (mt * 16 + l15) * 8;
      short8 a0 = *(const short8*)&Ks[(rb + sw0) * 8];
      short8 a1 = *(const short8*)&Ks[(rb + sw1) * 8];
#pragma unroll
      for (int qnt = 0; qnt < 2; qnt++) {
        float4a s = (float4a){0.f, 0.f, 0.f, 0.f};
        s = __builtin_amdgcn_mfma_f32_16x16x32_bf16(a0, qf[qnt][0], s, 0, 0, 0);
        s = __builtin_amdgcn_mfma_f32_16x16x32_bf16(a1, qf[qnt][1], s, 0, 0, 0);
        uint2 pk;
        pk.x = pack_bf16(__builtin_amdgcn_exp2f(s[0]), __builtin_amdgcn_exp2f(s[1]));
        pk.y = pack_bf16(__builtin_amdgcn_exp2f(s[2]), __builtin_amdgcn_exp2f(s[3]));
        *(uint2*)&Ps[w][qnt * 16 + l15][mt * 16 + quad * 4] = pk;
      }
    }
    asm volatile("s_waitcnt lgkmcnt(0)" ::: "memory");  // P write->read, same wave

    // O += P·V ; l += P·1 (MFMA)
#pragma unroll
    for (int c = 0; c < 2; c++) {
      short8 pa0 = *(const short8*)&Ps[w][l15][c * 32 + quad * 8];
      short8 pa1 = *(const short8*)&Ps[w][16 + l15][c * 32 + quad * 8];
      Lacc[0] = __builtin_amdgcn_mfma_f32_16x16x32_bf16(pa0, ones, Lacc[0], 0, 0, 0);
      Lacc[1] = __builtin_amdgcn_mfma_f32_16x16x32_bf16(pa1, ones, Lacc[1], 0, 0, 0);
      const int vsw = (c * 4 + quad + l15) & 7;
#pragma unroll
      for (int nt = 0; nt < 4; nt++) {
        short8 vb = *(const short8*)&Vs[((nt * 16 + l15) * 8 + vsw) * 8];
        Oacc[0][nt] = __builtin_amdgcn_mfma_f32_16x16x32_bf16(pa0, vb, Oacc[0][nt], 0, 0, 0);
        Oacc[1][nt] = __builtin_amdgcn_mfma_f32_16x16x32_bf16(pa1, vb, Oacc[1][nt], 0, 0, 0);
      }
    }
  }

  if (l15 == 0) {
#pragma unroll
    for (int qnt = 0; qnt < 2; qnt++)
#pragma unroll
      for (int reg = 0; reg < 4; reg++) {
        const int q = qb * 128 + w * 32 + qnt * 16 + quad * 4 + reg;
        Lp[(size_t)sp * ROWS * NH + ((size_t)bb * S_LEN + q) * NH + h] = Lacc[qnt][reg];
      }
  }

  unsigned short* Ob = Op + (size_t)sp * ROWS * D_MODEL;
#pragma unroll
  for (int qnt = 0; qnt < 2; qnt++) {
#pragma unroll
    for (int reg = 0; reg < 4; reg++) {
      const int q = qb * 128 + w * 32 + qnt * 16 + quad * 4 + reg;
      unsigned short* orow = Ob + ((size_t)bb * S_LEN + q) * D_MODEL + h * HD;
#pragma unroll
      for (int nt = 0; nt < 4; nt++)
        orow[nt * 16 + l15] = f2bf(Oacc[qnt][nt][reg]);
    }
  }
}

extern "C" void kernel_launch(void* const* d_in, const int* in_sizes, int n_in,
                              void* d_out, int out_size, void* d_ws, size_t ws_size,
                              hipStream_t stream) {
  const float* query = (const float*)d_in[0];
  const float* key   = (const float*)d_in[1];
  const float* value = (const float*)d_in[2];
  const float* Wq = (const float*)d_in[3];
  const float* bq = (const float*)d_in[4];
  const float* Wk = (const float*)d_in[5];
  const float* bk = (const float*)d_in[6];
  const float* Wv = (const float*)d_in[7];
  const float* bv = (const float*)d_in[8];
  const float* Wo = (const float*)d_in[9];
  const float* bo = (const float*)d_in[10];
  float* out = (float*)d_out;

  char* ws = (char*)d_ws;
  const size_t MB = 1024 * 1024;
  unsigned short* wq16 = (unsigned short*)(ws + 24 * MB);
  unsigned short* wk16 = (unsigned short*)(ws + 26 * MB);
  unsigned short* wv16 = (unsigned short*)(ws + 28 * MB);
  unsigned short* qbuf  = (unsigned short*)(ws + 32 * MB);
  unsigned short* kbuf  = (unsigned short*)(ws + 40 * MB);
  unsigned short* vtbuf = (unsigned short*)(ws + 48 * MB);
  unsigned short* wo16  = (unsigned short*)(ws + 56 * MB);
  float* Lp = (float*)(ws + 58 * MB);
  unsigned short* Op = (unsigned short*)(ws + 0 * MB);  // 2 x 8 MB bf16 partials

  ConvArgs ca;
  const int NW = D_MODEL * D_MODEL;
  ca.s[0] = Wq; ca.d[0] = wq16; ca.n[0] = NW;
  ca.s[1] = Wk; ca.d[1] = wk16; ca.n[1] = NW;
  ca.s[2] = Wv; ca.d[2] = wv16; ca.n[2] = NW;
  ca.s[3] = Wo; ca.d[3] = wo16; ca.n[3] = NW;
  hipLaunchKernelGGL(convert_bf16, dim3(NW / 2048, 4), dim3(256), 0, stream, ca);

  dim3 gqkv(ROWS / 128, D_MODEL / 128, 3);  // 768 blocks
  hipLaunchKernelGGL(gemm_qkv, gqkv, dim3(256), 0, stream,
                     query, key, value, wq16, wk16, wv16, bq, bk, bv,
                     qbuf, kbuf, vtbuf);

  hipLaunchKernelGGL(attn_kernel, dim3(1024), dim3(256), 0, stream,
                     qbuf, kbuf, vtbuf, Op, Lp);

  dim3 go(ROWS / 64, D_MODEL / 128);        // 512 blocks
  hipLaunchKernelGGL(gemm_o, go, dim3(256), 0, stream, Op, Lp, wo16, bo, out);
}